// Round 1
// baseline (1032.616 us; speedup 1.0000x reference)
//
#include <hip/hip_runtime.h>
#include <hip/hip_bf16.h>
#include <stdint.h>

typedef __bf16 bf16x8 __attribute__((ext_vector_type(8)));
typedef float f32x4 __attribute__((ext_vector_type(4)));

__device__ __forceinline__ unsigned short f2bf(float f) {
  union { float f; unsigned int u; } v; v.f = f;
  unsigned int u = v.u;
  unsigned int r = (u + 0x7fffu + ((u >> 16) & 1u)) >> 16;
  return (unsigned short)r;
}

// ---------------- elementwise fp32 -> bf16 (x) ----------------
__global__ __launch_bounds__(256) void conv_f2bf(const float* __restrict__ in,
                                                 unsigned short* __restrict__ out, int n4) {
  int i = blockIdx.x * 256 + threadIdx.x;
  if (i < n4) {
    float4 v = ((const float4*)in)[i];
    ushort4 o;
    o.x = f2bf(v.x); o.y = f2bf(v.y); o.z = f2bf(v.z); o.w = f2bf(v.w);
    ((ushort4*)out)[i] = o;
  }
}

// ---------------- W [K][N] fp32 -> Wt [N][K] bf16 ----------------
__global__ __launch_bounds__(256) void conv_wt(const float* __restrict__ W,
                                               unsigned short* __restrict__ Wt,
                                               int K, int N) {
  __shared__ __align__(16) unsigned short t[64][65];
  int k0 = blockIdx.x * 64, n0 = blockIdx.y * 64;
  for (int i = 0; i < 16; i++) {
    int e = threadIdx.x + i * 256;
    int r = e >> 6, c = e & 63;
    t[r][c] = f2bf(W[(size_t)(k0 + r) * N + n0 + c]);
  }
  __syncthreads();
  for (int i = 0; i < 16; i++) {
    int e = threadIdx.x + i * 256;
    int r = e >> 6, c = e & 63;
    Wt[(size_t)(n0 + r) * K + k0 + c] = t[c][r];
  }
}

// ---------------- v_lin [S][1536] fp32 -> vt [12][128][S] bf16 ----------------
__global__ __launch_bounds__(256) void conv_vt(const float* __restrict__ vlin,
                                               unsigned short* __restrict__ vt, int S) {
  __shared__ __align__(16) unsigned short t[64][65];
  int s0 = blockIdx.x * 64, d0 = blockIdx.y * 64;
  for (int i = 0; i < 16; i++) {
    int e = threadIdx.x + i * 256;
    int r = e >> 6, c = e & 63;
    t[r][c] = f2bf(vlin[(size_t)(s0 + r) * 1536 + d0 + c]);
  }
  __syncthreads();
  for (int i = 0; i < 16; i++) {
    int e = threadIdx.x + i * 256;
    int r = e >> 6, c = e & 63;   // r: d-offset, c: s-offset
    int d = d0 + r;
    int h = d >> 7, dd = d & 127;
    vt[((size_t)h * 128 + dd) * S + s0 + c] = t[c][r];
  }
}

// ---------------- GEMM: C[M][N] = A[M][K](bf16) @ Bt[N][K](bf16)^T + bias, fp32 out ----
// 64x64 tile, 4 waves, wave w -> rows [w*16, w*16+16), 4 n-subtiles of 16.
__global__ __launch_bounds__(256) void gemm_bf16(
    const unsigned short* __restrict__ A, const unsigned short* __restrict__ Bt,
    const float* __restrict__ bias, float* __restrict__ C, int M, int N, int K) {
  __shared__ __align__(16) unsigned short As[64][72];
  __shared__ __align__(16) unsigned short Bs[64][72];
  int tid = threadIdx.x;
  int wave = tid >> 6, lane = tid & 63;
  int quad = lane >> 4, l16 = lane & 15;
  int m0 = blockIdx.x * 64, n0 = blockIdx.y * 64;
  f32x4 acc[4] = {};
  for (int k0 = 0; k0 < K; k0 += 64) {
    for (int i = 0; i < 4; i++) {
      int v = tid + i * 256;              // 0..1023
      int r = v >> 4, c4 = (v & 15) << 2; // 16 ushort4 per 64-col row
      *(ushort4*)&As[r][c4] = *(const ushort4*)&A[(size_t)(m0 + r) * K + k0 + c4];
      *(ushort4*)&Bs[r][c4] = *(const ushort4*)&Bt[(size_t)(n0 + r) * K + k0 + c4];
    }
    __syncthreads();
    for (int kk = 0; kk < 64; kk += 32) {
      bf16x8 af = *(const bf16x8*)&As[wave * 16 + l16][kk + quad * 8];
      for (int nt = 0; nt < 4; nt++) {
        bf16x8 bfrag = *(const bf16x8*)&Bs[nt * 16 + l16][kk + quad * 8];
        acc[nt] = __builtin_amdgcn_mfma_f32_16x16x32_bf16(af, bfrag, acc[nt], 0, 0, 0);
      }
    }
    __syncthreads();
  }
  for (int nt = 0; nt < 4; nt++) {
    int col = n0 + nt * 16 + l16;
    float b = bias[col];
    for (int r = 0; r < 4; r++) {
      int row = m0 + wave * 16 + quad * 4 + r;
      C[(size_t)row * N + col] = acc[nt][r] + b;
    }
  }
}

// ---------------- RMS norm row-wise: out = bf16(u * rsqrt(mean(u^2)+eps) * g) ----------
__global__ __launch_bounds__(256) void rms_bf16(const float* __restrict__ lin,
                                                const float* __restrict__ g,
                                                unsigned short* __restrict__ out) {
  const int N = 1536;
  int row = blockIdx.x;
  const float* p = lin + (size_t)row * N;
  float vals[6];
  float ss = 0.f;
  for (int j = 0; j < 6; j++) {
    float v = p[threadIdx.x + j * 256];
    vals[j] = v; ss += v * v;
  }
  for (int o = 32; o > 0; o >>= 1) ss += __shfl_down(ss, o);
  __shared__ float red[4];
  if ((threadIdx.x & 63) == 0) red[threadIdx.x >> 6] = ss;
  __syncthreads();
  float tot = red[0] + red[1] + red[2] + red[3];
  float sc = rsqrtf(tot * (1.0f / N) + 1e-5f);
  unsigned short* po = out + (size_t)row * N;
  for (int j = 0; j < 6; j++) {
    int c = threadIdx.x + j * 256;
    po[c] = f2bf(vals[j] * sc * g[c]);
  }
}

// ---------------- flash attention, one block = (64 q rows) x (1 head) ----------------
__global__ __launch_bounds__(256) void attn(
    const unsigned short* __restrict__ qb, const unsigned short* __restrict__ kb,
    const unsigned short* __restrict__ vt,
    const int* __restrict__ seq, const int* __restrict__ fr, const int* __restrict__ nz,
    const int* __restrict__ wsz,
    unsigned short* __restrict__ ob, int S) {
  const int D = 1536;
  int h = blockIdx.y;
  int q0 = blockIdx.x * 64;
  int tid = threadIdx.x, wave = tid >> 6, lane = tid & 63;
  int quad = lane >> 4, l16 = lane & 15;
  int W = wsz[0];
  const float scale = 0.088388347648318447f; // 1/sqrt(128)

  // Q fragments (A-operand): row = q, k = dhead. Wave handles rows wave*16..+16.
  bf16x8 qf[4];
  int qrow = q0 + wave * 16 + l16;
  for (int ks = 0; ks < 4; ks++)
    qf[ks] = *(const bf16x8*)&qb[(size_t)qrow * D + h * 128 + ks * 32 + quad * 8];

  // ids for the 4 q-rows this lane's accumulator registers cover (row = quad*4+r)
  int qseq[4], qfr[4], qnz[4];
  for (int r = 0; r < 4; r++) {
    int q = q0 + wave * 16 + quad * 4 + r;
    qseq[r] = seq[q]; qfr[r] = fr[q]; qnz[r] = nz[q];
  }

  f32x4 oacc[8] = {};
  float m_i[4], l_i[4];
  for (int r = 0; r < 4; r++) { m_i[r] = -1e9f; l_i[r] = 0.f; }

  __shared__ __align__(16) unsigned short pshare[4][16][40];
  const unsigned short* vth = vt + (size_t)h * 128 * S;

  for (int k0 = 0; k0 < S; k0 += 32) {
    // scores: 16q x 32k per wave (2 n-subtiles of 16 keys)
    f32x4 sacc[2] = {};
    for (int nt = 0; nt < 2; nt++) {
      int krow = k0 + nt * 16 + l16;
      const unsigned short* kp = &kb[(size_t)krow * D + h * 128 + quad * 8];
      for (int ks = 0; ks < 4; ks++) {
        bf16x8 kf = *(const bf16x8*)&kp[ks * 32];
        sacc[nt] = __builtin_amdgcn_mfma_f32_16x16x32_bf16(qf[ks], kf, sacc[nt], 0, 0, 0);
      }
    }
    // mask + online softmax (fp32)
    float pv[2][4];
    for (int nt = 0; nt < 2; nt++) {
      int k = k0 + nt * 16 + l16;
      int ksq = seq[k], kfr = fr[k], knz = nz[k];
      for (int r = 0; r < 4; r++) {
        float s = sacc[nt][r] * scale;
        bool ok  = (qseq[r] == ksq) && (qseq[r] >= 0) && (ksq >= 0);
        bool c2c = (qnz[r] == 1) && (knz == 1) && (kfr <= qfr[r]);
        bool n2c = (qnz[r] == 0) && (knz == 1) && (kfr <  qfr[r]);
        bool n2n = (qnz[r] == 0) && (knz == 0) && (kfr == qfr[r]);
        int df = qfr[r] - kfr; df = df < 0 ? -df : df;
        bool msk = (c2c || n2c || n2n) && ok && (df <= W);
        pv[nt][r] = msk ? s : -1e9f;
      }
    }
    for (int r = 0; r < 4; r++) {
      float mx = fmaxf(pv[0][r], pv[1][r]);
      for (int o = 1; o < 16; o <<= 1) mx = fmaxf(mx, __shfl_xor(mx, o));
      float mnew = fmaxf(m_i[r], mx);
      float alpha = __expf(m_i[r] - mnew);
      m_i[r] = mnew;
      float rs = 0.f;
      for (int nt = 0; nt < 2; nt++) { pv[nt][r] = __expf(pv[nt][r] - mnew); rs += pv[nt][r]; }
      for (int o = 1; o < 16; o <<= 1) rs += __shfl_xor(rs, o);
      l_i[r] = l_i[r] * alpha + rs;
      for (int d = 0; d < 8; d++) oacc[d][r] *= alpha;
    }
    // P: C/D layout -> A-operand layout via per-wave LDS round-trip
    for (int nt = 0; nt < 2; nt++)
      for (int r = 0; r < 4; r++)
        pshare[wave][quad * 4 + r][nt * 16 + l16] = f2bf(pv[nt][r]);
    __syncthreads();   // drains lgkm: writes visible before read
    bf16x8 pf = *(const bf16x8*)&pshare[wave][l16][quad * 8];
    for (int d = 0; d < 8; d++) {
      bf16x8 vf = *(const bf16x8*)&vth[(size_t)(d * 16 + l16) * S + k0 + quad * 8];
      oacc[d] = __builtin_amdgcn_mfma_f32_16x16x32_bf16(pf, vf, oacc[d], 0, 0, 0);
    }
    __syncthreads();
  }

  for (int r = 0; r < 4; r++) {
    int q = q0 + wave * 16 + quad * 4 + r;
    float inv = (qseq[r] >= 0) ? 1.0f / l_i[r] : 0.0f;
    for (int d = 0; d < 8; d++)
      ob[(size_t)q * D + h * 128 + d * 16 + l16] = f2bf(oacc[d][r] * inv);
  }
}

extern "C" void kernel_launch(void* const* d_in, const int* in_sizes, int n_in,
                              void* d_out, int out_size, void* d_ws, size_t ws_size,
                              hipStream_t stream) {
  const float* x  = (const float*)d_in[0];
  const float* Wq = (const float*)d_in[1];
  const float* bq = (const float*)d_in[2];
  const float* Wk = (const float*)d_in[3];
  const float* bk = (const float*)d_in[4];
  const float* Wv = (const float*)d_in[5];
  const float* bv = (const float*)d_in[6];
  const float* gq = (const float*)d_in[7];
  const float* gk = (const float*)d_in[8];
  const float* Wo = (const float*)d_in[9];
  const float* bo = (const float*)d_in[10];
  const int* seq  = (const int*)d_in[11];
  const int* fr   = (const int*)d_in[12];
  const int* nz   = (const int*)d_in[13];
  const int* wsz  = (const int*)d_in[14];
  float* out = (float*)d_out;
  const int S = in_sizes[11];   // 3072
  const int D = 1536;

  size_t bfsz  = (size_t)S * D * 2;
  size_t wtsz  = (size_t)D * D * 2;
  size_t linsz = (size_t)S * D * 4;
  char* ws = (char*)d_ws;
  unsigned short* x_bf = (unsigned short*)ws;
  unsigned short* wt   = (unsigned short*)(ws + bfsz);
  float*          lin  = (float*)(ws + bfsz + wtsz);
  unsigned short* q_bf = (unsigned short*)(ws + bfsz + wtsz + linsz);
  unsigned short* k_bf = (unsigned short*)(ws + 2 * bfsz + wtsz + linsz);
  unsigned short* vtb  = (unsigned short*)(ws + 3 * bfsz + wtsz + linsz);
  unsigned short* o_bf = (unsigned short*)(ws + 4 * bfsz + wtsz + linsz);

  dim3 blk(256);
  dim3 gConv((S * D / 4 + 255) / 256);
  dim3 gWt(D / 64, D / 64);
  dim3 gGemm(S / 64, D / 64);
  dim3 gVt(S / 64, D / 64);
  dim3 gAttn(S / 64, D / 128);

  conv_f2bf<<<gConv, blk, 0, stream>>>(x, x_bf, S * D / 4);

  conv_wt<<<gWt, blk, 0, stream>>>(Wq, wt, D, D);
  gemm_bf16<<<gGemm, blk, 0, stream>>>(x_bf, wt, bq, lin, S, D, D);
  rms_bf16<<<dim3(S), blk, 0, stream>>>(lin, gq, q_bf);

  conv_wt<<<gWt, blk, 0, stream>>>(Wk, wt, D, D);
  gemm_bf16<<<gGemm, blk, 0, stream>>>(x_bf, wt, bk, lin, S, D, D);
  rms_bf16<<<dim3(S), blk, 0, stream>>>(lin, gk, k_bf);

  conv_wt<<<gWt, blk, 0, stream>>>(Wv, wt, D, D);
  gemm_bf16<<<gGemm, blk, 0, stream>>>(x_bf, wt, bv, lin, S, D, D);
  conv_vt<<<gVt, blk, 0, stream>>>(lin, vtb, S);

  attn<<<gAttn, blk, 0, stream>>>(q_bf, k_bf, vtb, seq, fr, nz, wsz, o_bf, S);

  conv_wt<<<gWt, blk, 0, stream>>>(Wo, wt, D, D);
  gemm_bf16<<<gGemm, blk, 0, stream>>>(o_bf, wt, bo, out, S, D, D);
}

// Round 2
// 532.755 us; speedup vs baseline: 1.9383x; 1.9383x over previous
//
#include <hip/hip_runtime.h>
#include <hip/hip_bf16.h>
#include <stdint.h>

typedef __bf16 bf16x8 __attribute__((ext_vector_type(8)));
typedef float f32x4 __attribute__((ext_vector_type(4)));

__device__ __forceinline__ unsigned short f2bf(float f) {
  union { float f; unsigned int u; } v; v.f = f;
  unsigned int u = v.u;
  unsigned int r = (u + 0x7fffu + ((u >> 16) & 1u)) >> 16;
  return (unsigned short)r;
}

// ---------------- elementwise fp32 -> bf16 (x) ----------------
__global__ __launch_bounds__(256) void conv_f2bf(const float* __restrict__ in,
                                                 unsigned short* __restrict__ out, int n4) {
  int i = blockIdx.x * 256 + threadIdx.x;
  if (i < n4) {
    float4 v = ((const float4*)in)[i];
    ushort4 o;
    o.x = f2bf(v.x); o.y = f2bf(v.y); o.z = f2bf(v.z); o.w = f2bf(v.w);
    ((ushort4*)out)[i] = o;
  }
}

// ---------------- W [K][N] fp32 -> Wt [N][K] bf16 ----------------
__global__ __launch_bounds__(256) void conv_wt(const float* __restrict__ W,
                                               unsigned short* __restrict__ Wt,
                                               int K, int N) {
  __shared__ __align__(16) unsigned short t[64][65];
  int k0 = blockIdx.x * 64, n0 = blockIdx.y * 64;
  for (int i = 0; i < 16; i++) {
    int e = threadIdx.x + i * 256;
    int r = e >> 6, c = e & 63;
    t[r][c] = f2bf(W[(size_t)(k0 + r) * N + n0 + c]);
  }
  __syncthreads();
  for (int i = 0; i < 16; i++) {
    int e = threadIdx.x + i * 256;
    int r = e >> 6, c = e & 63;
    Wt[(size_t)(n0 + r) * K + k0 + c] = t[c][r];
  }
}

// ---------------- v_lin [S][1536] fp32 -> vt [12][128][S] bf16 ----------------
__global__ __launch_bounds__(256) void conv_vt(const float* __restrict__ vlin,
                                               unsigned short* __restrict__ vt, int S) {
  __shared__ __align__(16) unsigned short t[64][65];
  int s0 = blockIdx.x * 64, d0 = blockIdx.y * 64;
  for (int i = 0; i < 16; i++) {
    int e = threadIdx.x + i * 256;
    int r = e >> 6, c = e & 63;
    t[r][c] = f2bf(vlin[(size_t)(s0 + r) * 1536 + d0 + c]);
  }
  __syncthreads();
  for (int i = 0; i < 16; i++) {
    int e = threadIdx.x + i * 256;
    int r = e >> 6, c = e & 63;   // r: d-offset, c: s-offset
    int d = d0 + r;
    int h = d >> 7, dd = d & 127;
    vt[((size_t)h * 128 + dd) * S + s0 + c] = t[c][r];
  }
}

// ---------------- GEMM m97-style: 128x128 tile, global_load_lds, BK=64 ------------
// C[M][N] = A[M][K](bf16) @ Bt[N][K](bf16)^T + bias (fp32 out)
__global__ __launch_bounds__(256) void gemm128(
    const unsigned short* __restrict__ A, const unsigned short* __restrict__ Bt,
    const float* __restrict__ bias, float* __restrict__ C, int M, int N, int K) {
  __shared__ __align__(16) unsigned short As[128 * 64];
  __shared__ __align__(16) unsigned short Bs[128 * 64];
  int tid = threadIdx.x, wave = tid >> 6, lane = tid & 63;
  int quad = lane >> 4, l16 = lane & 15;
  int m0 = blockIdx.x * 128, n0 = blockIdx.y * 128;
  int wm = (wave & 1) * 64, wn = (wave >> 1) * 64;
  int lr = lane >> 3;          // 0..7  (row within 8-row chunk)
  int lc = (lane & 7) * 8;     // element col (8 bf16 = 16B)
  f32x4 acc[4][4] = {};
  for (int k0 = 0; k0 < K; k0 += 64) {
    for (int c = 0; c < 4; c++) {
      int chunk = wave * 4 + c;          // 0..15, wave-uniform
      int row = chunk * 8 + lr;          // 0..127
      const unsigned short* ga = &A[(size_t)(m0 + row) * K + k0 + lc];
      const unsigned short* gb = &Bt[(size_t)(n0 + row) * K + k0 + lc];
      __builtin_amdgcn_global_load_lds(
          (const __attribute__((address_space(1))) unsigned int*)ga,
          (__attribute__((address_space(3))) unsigned int*)(As + chunk * 512), 16, 0, 0);
      __builtin_amdgcn_global_load_lds(
          (const __attribute__((address_space(1))) unsigned int*)gb,
          (__attribute__((address_space(3))) unsigned int*)(Bs + chunk * 512), 16, 0, 0);
    }
    __syncthreads();
    for (int kk = 0; kk < 64; kk += 32) {
      bf16x8 af[4], bfr[4];
      for (int i = 0; i < 4; i++)
        af[i] = *(const bf16x8*)&As[(wm + i * 16 + l16) * 64 + kk + quad * 8];
      for (int j = 0; j < 4; j++)
        bfr[j] = *(const bf16x8*)&Bs[(wn + j * 16 + l16) * 64 + kk + quad * 8];
      for (int i = 0; i < 4; i++)
        for (int j = 0; j < 4; j++)
          acc[i][j] = __builtin_amdgcn_mfma_f32_16x16x32_bf16(af[i], bfr[j], acc[i][j], 0, 0, 0);
    }
    __syncthreads();
  }
  for (int j = 0; j < 4; j++) {
    int col = n0 + wn + j * 16 + l16;
    float b = bias[col];
    for (int i = 0; i < 4; i++)
      for (int r = 0; r < 4; r++)
        C[(size_t)(m0 + wm + i * 16 + quad * 4 + r) * N + col] = acc[i][j][r] + b;
  }
}

// ---------------- RMS norm row-wise: out = bf16(u * rsqrt(mean(u^2)+eps) * g) ----------
__global__ __launch_bounds__(256) void rms_bf16(const float* __restrict__ lin,
                                                const float* __restrict__ g,
                                                unsigned short* __restrict__ out) {
  const int N = 1536;
  int row = blockIdx.x;
  const float* p = lin + (size_t)row * N;
  float vals[6];
  float ss = 0.f;
  for (int j = 0; j < 6; j++) {
    float v = p[threadIdx.x + j * 256];
    vals[j] = v; ss += v * v;
  }
  for (int o = 32; o > 0; o >>= 1) ss += __shfl_down(ss, o);
  __shared__ float red[4];
  if ((threadIdx.x & 63) == 0) red[threadIdx.x >> 6] = ss;
  __syncthreads();
  float tot = red[0] + red[1] + red[2] + red[3];
  float sc = rsqrtf(tot * (1.0f / N) + 1e-5f);
  unsigned short* po = out + (size_t)row * N;
  for (int j = 0; j < 6; j++) {
    int c = threadIdx.x + j * 256;
    po[c] = f2bf(vals[j] * sc * g[c]);
  }
}

// ---------------- flash attention with mask-structure tile skipping ----------------
// block = 64 q rows x 1 head; 4 independent waves of 16 q rows (no in-loop barriers).
__global__ __launch_bounds__(256) void attn(
    const unsigned short* __restrict__ qb, const unsigned short* __restrict__ kb,
    const unsigned short* __restrict__ vt,
    const int* __restrict__ seq, const int* __restrict__ fr, const int* __restrict__ nz,
    const int* __restrict__ wsz,
    unsigned short* __restrict__ ob, int S) {
  const int D = 1536;
  int h = blockIdx.y;
  int q0 = blockIdx.x * 64;
  int tid = threadIdx.x, wave = tid >> 6, lane = tid & 63;
  int quad = lane >> 4, l16 = lane & 15;
  int W = wsz[0];
  const float scale = 0.088388347648318447f; // 1/sqrt(128)

  __shared__ int kid_s[3072];
  __shared__ unsigned int tmask_s[96];
  __shared__ __align__(16) unsigned short pshare[4][16][40];

  // stage packed ids: valid<<9 | nz<<8 | frame(0..15) | seq<<10
  for (int i = tid; i < S; i += 256) {
    int sq = seq[i];
    kid_s[i] = (sq < 0) ? 0 : ((1 << 9) | ((nz[i] & 1) << 8) | (fr[i] & 15) | (sq << 10));
  }
  __syncthreads();
  // per-32-key-tile frame occupancy: nz0 frames low16, nz1 frames high16
  for (int t = tid; t < S / 32; t += 256) {
    unsigned int m = 0;
    for (int j = 0; j < 32; j++) {
      int a = kid_s[t * 32 + j];
      if (a & (1 << 9)) {
        int f = a & 15;
        m |= (a & (1 << 8)) ? (1u << (16 + f)) : (1u << f);
      }
    }
    tmask_s[t] = m;
  }
  __syncthreads();
  // ---- after this point waves are fully independent ----

  int qbase = q0 + wave * 16;
  // per-lane q ids for the 4 accumulator rows
  int aq[4];
  for (int r = 0; r < 4; r++) aq[r] = kid_s[qbase + quad * 4 + r];

  // wave-uniform allowed-frame mask over the wave's 16 q rows
  unsigned int allowed = 0;
  for (int j = 0; j < 16; j++) {
    int a = kid_s[qbase + j];
    if (!(a & (1 << 9))) continue;
    int fq = a & 15, nq = (a >> 8) & 1;
    int lo = fq - W; if (lo < 0) lo = 0;
    unsigned int lom = ~((1u << lo) - 1);
    if (nq) {
      allowed |= (((1u << (fq + 1)) - 1) & lom) << 16;  // c2c: nz1 keys [lo, fq]
    } else {
      allowed |= (((1u << fq) - 1) & lom) << 16;        // n2c: nz1 keys [lo, fq-1]
      allowed |= (1u << fq);                            // n2n: nz0 keys {fq}
    }
  }

  // Q fragments (A-operand)
  bf16x8 qf[4];
  int qrow = qbase + l16;
  for (int ks = 0; ks < 4; ks++)
    qf[ks] = *(const bf16x8*)&qb[(size_t)qrow * D + h * 128 + ks * 32 + quad * 8];

  f32x4 oacc[8] = {};
  float m_i[4], l_i[4];
  for (int r = 0; r < 4; r++) { m_i[r] = -1e9f; l_i[r] = 0.f; }
  const unsigned short* vth = vt + (size_t)h * 128 * S;

  for (int k0 = 0; k0 < S; k0 += 32) {
    if ((tmask_s[k0 >> 5] & allowed) == 0) continue;   // fully masked tile

    // scores: 16q x 32k (2 n-subtiles of 16 keys)
    f32x4 sacc[2] = {};
    for (int nt = 0; nt < 2; nt++) {
      const unsigned short* kp = &kb[(size_t)(k0 + nt * 16 + l16) * D + h * 128 + quad * 8];
      for (int ks = 0; ks < 4; ks++) {
        bf16x8 kf = *(const bf16x8*)&kp[ks * 32];
        sacc[nt] = __builtin_amdgcn_mfma_f32_16x16x32_bf16(qf[ks], kf, sacc[nt], 0, 0, 0);
      }
    }
    // mask + online softmax (fp32)
    int ak[2] = { kid_s[k0 + l16], kid_s[k0 + 16 + l16] };
    float pv[2][4];
    for (int nt = 0; nt < 2; nt++) {
      int a = ak[nt];
      int kfr = a & 15, knz = (a >> 8) & 1, kvb = (a >> 9) & 1, ksq = a >> 10;
      for (int r = 0; r < 4; r++) {
        int b = aq[r];
        int qfr = b & 15, qnzb = (b >> 8) & 1, qvb = (b >> 9) & 1, qsq = b >> 10;
        bool ok  = qvb && kvb && (qsq == ksq);
        bool c2c = qnzb && knz && (kfr <= qfr);
        bool n2c = !qnzb && knz && (kfr < qfr);
        bool n2n = !qnzb && !knz && (kfr == qfr);
        int df = qfr - kfr; df = df < 0 ? -df : df;
        bool msk = (c2c || n2c || n2n) && ok && (df <= W);
        pv[nt][r] = msk ? sacc[nt][r] * scale : -1e9f;
      }
    }
    for (int r = 0; r < 4; r++) {
      float mx = fmaxf(pv[0][r], pv[1][r]);
      for (int o = 1; o < 16; o <<= 1) mx = fmaxf(mx, __shfl_xor(mx, o));
      float mnew = fmaxf(m_i[r], mx);
      float alpha = __expf(m_i[r] - mnew);
      m_i[r] = mnew;
      float rs = 0.f;
      for (int nt = 0; nt < 2; nt++) { pv[nt][r] = __expf(pv[nt][r] - mnew); rs += pv[nt][r]; }
      for (int o = 1; o < 16; o <<= 1) rs += __shfl_xor(rs, o);
      l_i[r] = l_i[r] * alpha + rs;
      for (int d = 0; d < 8; d++) oacc[d][r] *= alpha;
    }
    // P: C/D layout -> A-operand layout via per-wave LDS round-trip (wave-local!)
    for (int nt = 0; nt < 2; nt++)
      for (int r = 0; r < 4; r++)
        pshare[wave][quad * 4 + r][nt * 16 + l16] = f2bf(pv[nt][r]);
    __asm__ __volatile__("s_waitcnt lgkmcnt(0)" ::: "memory");
    bf16x8 pf = *(const bf16x8*)&pshare[wave][l16][quad * 8];
    for (int d = 0; d < 8; d++) {
      bf16x8 vf = *(const bf16x8*)&vth[(size_t)(d * 16 + l16) * S + k0 + quad * 8];
      oacc[d] = __builtin_amdgcn_mfma_f32_16x16x32_bf16(pf, vf, oacc[d], 0, 0, 0);
    }
  }

  for (int r = 0; r < 4; r++) {
    int q = qbase + quad * 4 + r;
    float inv = (aq[r] & (1 << 9)) ? 1.0f / l_i[r] : 0.0f;
    for (int d = 0; d < 8; d++)
      ob[(size_t)q * D + h * 128 + d * 16 + l16] = f2bf(oacc[d][r] * inv);
  }
}

extern "C" void kernel_launch(void* const* d_in, const int* in_sizes, int n_in,
                              void* d_out, int out_size, void* d_ws, size_t ws_size,
                              hipStream_t stream) {
  const float* x  = (const float*)d_in[0];
  const float* Wq = (const float*)d_in[1];
  const float* bq = (const float*)d_in[2];
  const float* Wk = (const float*)d_in[3];
  const float* bk = (const float*)d_in[4];
  const float* Wv = (const float*)d_in[5];
  const float* bv = (const float*)d_in[6];
  const float* gq = (const float*)d_in[7];
  const float* gk = (const float*)d_in[8];
  const float* Wo = (const float*)d_in[9];
  const float* bo = (const float*)d_in[10];
  const int* seq  = (const int*)d_in[11];
  const int* fr   = (const int*)d_in[12];
  const int* nz   = (const int*)d_in[13];
  const int* wsz  = (const int*)d_in[14];
  float* out = (float*)d_out;
  const int S = in_sizes[11];   // 3072
  const int D = 1536;

  size_t bfsz  = (size_t)S * D * 2;
  size_t wtsz  = (size_t)D * D * 2;
  size_t linsz = (size_t)S * D * 4;
  char* ws = (char*)d_ws;
  unsigned short* x_bf = (unsigned short*)ws;
  unsigned short* wt   = (unsigned short*)(ws + bfsz);
  float*          lin  = (float*)(ws + bfsz + wtsz);
  unsigned short* q_bf = (unsigned short*)(ws + bfsz + wtsz + linsz);
  unsigned short* k_bf = (unsigned short*)(ws + 2 * bfsz + wtsz + linsz);
  unsigned short* vtb  = (unsigned short*)(ws + 3 * bfsz + wtsz + linsz);
  unsigned short* o_bf = (unsigned short*)(ws + 4 * bfsz + wtsz + linsz);

  dim3 blk(256);
  dim3 gConv((S * D / 4 + 255) / 256);
  dim3 gWt(D / 64, D / 64);
  dim3 gGemm(S / 128, D / 128);
  dim3 gVt(S / 64, D / 64);
  dim3 gAttn(S / 64, D / 128);

  conv_f2bf<<<gConv, blk, 0, stream>>>(x, x_bf, S * D / 4);

  conv_wt<<<gWt, blk, 0, stream>>>(Wq, wt, D, D);
  gemm128<<<gGemm, blk, 0, stream>>>(x_bf, wt, bq, lin, S, D, D);
  rms_bf16<<<dim3(S), blk, 0, stream>>>(lin, gq, q_bf);

  conv_wt<<<gWt, blk, 0, stream>>>(Wk, wt, D, D);
  gemm128<<<gGemm, blk, 0, stream>>>(x_bf, wt, bk, lin, S, D, D);
  rms_bf16<<<dim3(S), blk, 0, stream>>>(lin, gk, k_bf);

  conv_wt<<<gWt, blk, 0, stream>>>(Wv, wt, D, D);
  gemm128<<<gGemm, blk, 0, stream>>>(x_bf, wt, bv, lin, S, D, D);
  conv_vt<<<gVt, blk, 0, stream>>>(lin, vtb, S);

  attn<<<gAttn, blk, 0, stream>>>(q_bf, k_bf, vtb, seq, fr, nz, wsz, o_bf, S);

  conv_wt<<<gWt, blk, 0, stream>>>(Wo, wt, D, D);
  gemm128<<<gGemm, blk, 0, stream>>>(o_bf, wt, bo, out, S, D, D);
}

// Round 3
// 425.820 us; speedup vs baseline: 2.4250x; 1.2511x over previous
//
#include <hip/hip_runtime.h>
#include <hip/hip_bf16.h>
#include <stdint.h>

typedef __bf16 bf16x8 __attribute__((ext_vector_type(8)));
typedef float f32x4 __attribute__((ext_vector_type(4)));

__device__ __forceinline__ unsigned short f2bf(float f) {
  union { float f; unsigned int u; } v; v.f = f;
  unsigned int u = v.u;
  unsigned int r = (u + 0x7fffu + ((u >> 16) & 1u)) >> 16;
  return (unsigned short)r;
}

// ---------------- elementwise fp32 -> bf16 (x) ----------------
__global__ __launch_bounds__(256) void conv_f2bf(const float* __restrict__ in,
                                                 unsigned short* __restrict__ out, int n4) {
  int i = blockIdx.x * 256 + threadIdx.x;
  if (i < n4) {
    float4 v = ((const float4*)in)[i];
    ushort4 o;
    o.x = f2bf(v.x); o.y = f2bf(v.y); o.z = f2bf(v.z); o.w = f2bf(v.w);
    ((ushort4*)out)[i] = o;
  }
}

// ---------------- pack ids + per-32-key-tile occupancy masks ----------------
// kid: valid<<9 | nz<<8 | frame(0..15) | seq<<10 ; tmask: nz0 frames lo16, nz1 hi16
__global__ __launch_bounds__(256) void prep_ids(const int* __restrict__ seq,
                                                const int* __restrict__ fr,
                                                const int* __restrict__ nz,
                                                int* __restrict__ kid,
                                                unsigned int* __restrict__ tmask, int S) {
  __shared__ int ks_[3072];
  int tid = threadIdx.x;
  for (int i = tid; i < S; i += 256) {
    int sq = seq[i];
    int v = (sq < 0) ? 0 : ((1 << 9) | ((nz[i] & 1) << 8) | (fr[i] & 15) | (sq << 10));
    ks_[i] = v; kid[i] = v;
  }
  __syncthreads();
  for (int t = tid; t < S / 32; t += 256) {
    unsigned int m = 0;
    for (int j = 0; j < 32; j++) {
      int a = ks_[t * 32 + j];
      if (a & (1 << 9)) m |= (a & (1 << 8)) ? (1u << (16 + (a & 15))) : (1u << (a & 15));
    }
    tmask[t] = m;
  }
}

// ---------------- W [K][N] fp32 -> Wt [N][K] bf16 (single) ----------------
__global__ __launch_bounds__(256) void conv_wt(const float* __restrict__ W,
                                               unsigned short* __restrict__ Wt,
                                               int K, int N) {
  __shared__ __align__(16) unsigned short t[64][65];
  int k0 = blockIdx.x * 64, n0 = blockIdx.y * 64;
  for (int i = 0; i < 16; i++) {
    int e = threadIdx.x + i * 256;
    int r = e >> 6, c = e & 63;
    t[r][c] = f2bf(W[(size_t)(k0 + r) * N + n0 + c]);
  }
  __syncthreads();
  for (int i = 0; i < 16; i++) {
    int e = threadIdx.x + i * 256;
    int r = e >> 6, c = e & 63;
    Wt[(size_t)(n0 + r) * K + k0 + c] = t[c][r];
  }
}

// ---------------- Wq/Wk/Wv -> wt_cat[4608][1536] via blockIdx.z ----------------
__global__ __launch_bounds__(256) void conv_wt3(const float* __restrict__ W0,
                                                const float* __restrict__ W1,
                                                const float* __restrict__ W2,
                                                unsigned short* __restrict__ Wt) {
  const int K = 1536, N = 1536;
  const float* W = blockIdx.z == 0 ? W0 : (blockIdx.z == 1 ? W1 : W2);
  __shared__ __align__(16) unsigned short t[64][65];
  int k0 = blockIdx.x * 64, n0 = blockIdx.y * 64;
  for (int i = 0; i < 16; i++) {
    int e = threadIdx.x + i * 256;
    int r = e >> 6, c = e & 63;
    t[r][c] = f2bf(W[(size_t)(k0 + r) * N + n0 + c]);
  }
  __syncthreads();
  for (int i = 0; i < 16; i++) {
    int e = threadIdx.x + i * 256;
    int r = e >> 6, c = e & 63;
    Wt[(size_t)(blockIdx.z * 1536 + n0 + r) * K + k0 + c] = t[c][r];
  }
}

// ---------------- fused QKV GEMM: x_bf[S][1536] @ wt_cat[4608][1536]^T ----------
// region 0 -> linq fp32 (+bq), region 1 -> link fp32 (+bk), region 2 -> vtb bf16 transposed
__global__ __launch_bounds__(256) void gemm_qkv(
    const unsigned short* __restrict__ A, const unsigned short* __restrict__ Bt,
    const float* __restrict__ bq, const float* __restrict__ bk, const float* __restrict__ bv,
    float* __restrict__ linq, float* __restrict__ link, unsigned short* __restrict__ vtb,
    int S) {
  const int K = 1536;
  __shared__ __align__(16) unsigned short As[128 * 64];
  __shared__ __align__(16) unsigned short Bs[128 * 64];
  int tid = threadIdx.x, wave = tid >> 6, lane = tid & 63;
  int quad = lane >> 4, l16 = lane & 15;
  int m0 = blockIdx.x * 128, n0 = blockIdx.y * 128;
  int wm = (wave & 1) * 64, wn = (wave >> 1) * 64;
  int lr = lane >> 3, lc = (lane & 7) * 8;
  f32x4 acc[4][4] = {};
  for (int k0 = 0; k0 < K; k0 += 64) {
    for (int c = 0; c < 4; c++) {
      int chunk = wave * 4 + c;
      int row = chunk * 8 + lr;
      const unsigned short* ga = &A[(size_t)(m0 + row) * K + k0 + lc];
      const unsigned short* gb = &Bt[(size_t)(n0 + row) * K + k0 + lc];
      __builtin_amdgcn_global_load_lds(
          (const __attribute__((address_space(1))) unsigned int*)ga,
          (__attribute__((address_space(3))) unsigned int*)(As + chunk * 512), 16, 0, 0);
      __builtin_amdgcn_global_load_lds(
          (const __attribute__((address_space(1))) unsigned int*)gb,
          (__attribute__((address_space(3))) unsigned int*)(Bs + chunk * 512), 16, 0, 0);
    }
    __syncthreads();
    for (int kk = 0; kk < 64; kk += 32) {
      bf16x8 af[4], bfr[4];
      for (int i = 0; i < 4; i++)
        af[i] = *(const bf16x8*)&As[(wm + i * 16 + l16) * 64 + kk + quad * 8];
      for (int j = 0; j < 4; j++)
        bfr[j] = *(const bf16x8*)&Bs[(wn + j * 16 + l16) * 64 + kk + quad * 8];
      for (int i = 0; i < 4; i++)
        for (int j = 0; j < 4; j++)
          acc[i][j] = __builtin_amdgcn_mfma_f32_16x16x32_bf16(af[i], bfr[j], acc[i][j], 0, 0, 0);
    }
    __syncthreads();
  }
  int region = (n0 >= 3072) ? 2 : (n0 >= 1536 ? 1 : 0);
  int cbase = n0 - region * 1536;
  if (region < 2) {
    float* lin = region == 0 ? linq : link;
    const float* bias = region == 0 ? bq : bk;
    for (int j = 0; j < 4; j++) {
      int col = cbase + wn + j * 16 + l16;
      float b = bias[col];
      for (int i = 0; i < 4; i++)
        for (int r = 0; r < 4; r++)
          lin[(size_t)(m0 + wm + i * 16 + quad * 4 + r) * 1536 + col] = acc[i][j][r] + b;
    }
  } else {
    for (int j = 0; j < 4; j++) {
      int d = cbase + wn + j * 16 + l16;    // 0..1535
      float b = bv[d];
      int hh = d >> 7, dd = d & 127;
      unsigned short* vp = vtb + (size_t)(hh * 128 + dd) * S;
      for (int i = 0; i < 4; i++)
        for (int r = 0; r < 4; r++)
          vp[m0 + wm + i * 16 + quad * 4 + r] = f2bf(acc[i][j][r] + b);
    }
  }
}

// ---------------- GEMM 128x128 (Wo): fp32 out + bias ----------------
__global__ __launch_bounds__(256) void gemm128(
    const unsigned short* __restrict__ A, const unsigned short* __restrict__ Bt,
    const float* __restrict__ bias, float* __restrict__ C, int M, int N, int K) {
  __shared__ __align__(16) unsigned short As[128 * 64];
  __shared__ __align__(16) unsigned short Bs[128 * 64];
  int tid = threadIdx.x, wave = tid >> 6, lane = tid & 63;
  int quad = lane >> 4, l16 = lane & 15;
  int m0 = blockIdx.x * 128, n0 = blockIdx.y * 128;
  int wm = (wave & 1) * 64, wn = (wave >> 1) * 64;
  int lr = lane >> 3, lc = (lane & 7) * 8;
  f32x4 acc[4][4] = {};
  for (int k0 = 0; k0 < K; k0 += 64) {
    for (int c = 0; c < 4; c++) {
      int chunk = wave * 4 + c;
      int row = chunk * 8 + lr;
      const unsigned short* ga = &A[(size_t)(m0 + row) * K + k0 + lc];
      const unsigned short* gb = &Bt[(size_t)(n0 + row) * K + k0 + lc];
      __builtin_amdgcn_global_load_lds(
          (const __attribute__((address_space(1))) unsigned int*)ga,
          (__attribute__((address_space(3))) unsigned int*)(As + chunk * 512), 16, 0, 0);
      __builtin_amdgcn_global_load_lds(
          (const __attribute__((address_space(1))) unsigned int*)gb,
          (__attribute__((address_space(3))) unsigned int*)(Bs + chunk * 512), 16, 0, 0);
    }
    __syncthreads();
    for (int kk = 0; kk < 64; kk += 32) {
      bf16x8 af[4], bfr[4];
      for (int i = 0; i < 4; i++)
        af[i] = *(const bf16x8*)&As[(wm + i * 16 + l16) * 64 + kk + quad * 8];
      for (int j = 0; j < 4; j++)
        bfr[j] = *(const bf16x8*)&Bs[(wn + j * 16 + l16) * 64 + kk + quad * 8];
      for (int i = 0; i < 4; i++)
        for (int j = 0; j < 4; j++)
          acc[i][j] = __builtin_amdgcn_mfma_f32_16x16x32_bf16(af[i], bfr[j], acc[i][j], 0, 0, 0);
    }
    __syncthreads();
  }
  for (int j = 0; j < 4; j++) {
    int col = n0 + wn + j * 16 + l16;
    float b = bias[col];
    for (int i = 0; i < 4; i++)
      for (int r = 0; r < 4; r++)
        C[(size_t)(m0 + wm + i * 16 + quad * 4 + r) * N + col] = acc[i][j][r] + b;
  }
}

// ---------------- RMS norm row-wise ----------------
__global__ __launch_bounds__(256) void rms_bf16(const float* __restrict__ lin,
                                                const float* __restrict__ g,
                                                unsigned short* __restrict__ out) {
  const int N = 1536;
  int row = blockIdx.x;
  const float* p = lin + (size_t)row * N;
  float vals[6];
  float ss = 0.f;
  for (int j = 0; j < 6; j++) {
    float v = p[threadIdx.x + j * 256];
    vals[j] = v; ss += v * v;
  }
  for (int o = 32; o > 0; o >>= 1) ss += __shfl_down(ss, o);
  __shared__ float red[4];
  if ((threadIdx.x & 63) == 0) red[threadIdx.x >> 6] = ss;
  __syncthreads();
  float tot = red[0] + red[1] + red[2] + red[3];
  float sc = rsqrtf(tot * (1.0f / N) + 1e-5f);
  unsigned short* po = out + (size_t)row * N;
  for (int j = 0; j < 6; j++) {
    int c = threadIdx.x + j * 256;
    po[c] = f2bf(vals[j] * sc * g[c]);
  }
}

// ---------------- flash attention: 1 wave = 16 q rows x 1 head, pipelined ----------
__global__ __launch_bounds__(64) void attn(
    const unsigned short* __restrict__ qb, const unsigned short* __restrict__ kb,
    const unsigned short* __restrict__ vt,
    const int* __restrict__ kid, const unsigned int* __restrict__ tmask,
    const int* __restrict__ wsz,
    unsigned short* __restrict__ ob, int S) {
  const int D = 1536;
  const int h = blockIdx.y;
  const int qbase = blockIdx.x * 16;
  const int lane = threadIdx.x;
  const int quad = lane >> 4, l16 = lane & 15;
  const int W = wsz[0];
  const float scale = 0.088388347648318447f; // 1/sqrt(128)

  __shared__ __align__(16) unsigned short pshare[16][40];

  int kq = kid[qbase + l16];
  // wave-uniform allowed-frame mask (OR across the 16 q rows)
  unsigned int allowed = 0;
  if (kq & (1 << 9)) {
    int fq = kq & 15, nq = (kq >> 8) & 1;
    int lo = fq - W; if (lo < 0) lo = 0;
    unsigned int lom = ~((1u << lo) - 1);
    if (nq) allowed = (((1u << (fq + 1)) - 1) & lom) << 16;          // c2c
    else    allowed = ((((1u << fq) - 1) & lom) << 16) | (1u << fq); // n2c | n2n
  }
  for (int o = 1; o < 16; o <<= 1) allowed |= __shfl_xor(allowed, o);

  int aq[4];
  for (int r = 0; r < 4; r++) aq[r] = __shfl(kq, quad * 4 + r);

  // live-tile bitmap via ballot (96 tiles: 64 in bm0, 32 in bm1)
  unsigned long long bm0, bm1;
  {
    unsigned int ta = tmask[lane];
    bm0 = __ballot((ta & allowed) != 0);
    unsigned int tb = (lane < 32) ? tmask[64 + lane] : 0u;
    bm1 = __ballot((tb & allowed) != 0);
  }

  bf16x8 qf[4];
  {
    const unsigned short* qp = &qb[(size_t)(qbase + l16) * D + h * 128 + quad * 8];
    for (int ks = 0; ks < 4; ks++) qf[ks] = *(const bf16x8*)&qp[ks * 32];
  }

  f32x4 oacc[8] = {};
  float m_i[4], l_i[4];
  for (int r = 0; r < 4; r++) { m_i[r] = -1e9f; l_i[r] = 0.f; }
  const unsigned short* vth = vt + (size_t)h * 128 * S;

  int t;
  if (bm0) { t = __builtin_ctzll(bm0); bm0 &= bm0 - 1; }
  else if (bm1) { t = 64 + __builtin_ctzll(bm1); bm1 &= bm1 - 1; }
  else t = -1;

  bf16x8 kf[2][4]; int ak[2] = {0, 0};
  if (t >= 0) {
    ak[0] = kid[t * 32 + l16]; ak[1] = kid[t * 32 + 16 + l16];
    for (int nt = 0; nt < 2; nt++) {
      const unsigned short* kp = &kb[(size_t)(t * 32 + nt * 16 + l16) * D + h * 128 + quad * 8];
      for (int ks = 0; ks < 4; ks++) kf[nt][ks] = *(const bf16x8*)&kp[ks * 32];
    }
  }

  while (t >= 0) {
    int tn;
    if (bm0) { tn = __builtin_ctzll(bm0); bm0 &= bm0 - 1; }
    else if (bm1) { tn = 64 + __builtin_ctzll(bm1); bm1 &= bm1 - 1; }
    else tn = -1;
    // prefetch next tile's K + ids (hides under softmax)
    bf16x8 kf2[2][4]; int ak2[2] = {0, 0};
    if (tn >= 0) {
      ak2[0] = kid[tn * 32 + l16]; ak2[1] = kid[tn * 32 + 16 + l16];
      for (int nt = 0; nt < 2; nt++) {
        const unsigned short* kp = &kb[(size_t)(tn * 32 + nt * 16 + l16) * D + h * 128 + quad * 8];
        for (int ks = 0; ks < 4; ks++) kf2[nt][ks] = *(const bf16x8*)&kp[ks * 32];
      }
    }
    int k0 = t * 32;
    f32x4 sacc[2] = {};
    for (int nt = 0; nt < 2; nt++)
      for (int ks = 0; ks < 4; ks++)
        sacc[nt] = __builtin_amdgcn_mfma_f32_16x16x32_bf16(qf[ks], kf[nt][ks], sacc[nt], 0, 0, 0);
    // V loads issued before softmax (independent)
    bf16x8 vf[8];
    for (int d = 0; d < 8; d++)
      vf[d] = *(const bf16x8*)&vth[(size_t)(d * 16 + l16) * S + k0 + quad * 8];
    // mask
    float pv[2][4];
    for (int nt = 0; nt < 2; nt++) {
      int a = ak[nt];
      int kfr = a & 15, knz = (a >> 8) & 1, kvb = (a >> 9) & 1, ksq = a >> 10;
      for (int r = 0; r < 4; r++) {
        int b = aq[r];
        int qfr = b & 15, qnzb = (b >> 8) & 1, qvb = (b >> 9) & 1, qsq = b >> 10;
        bool ok  = qvb && kvb && (qsq == ksq);
        bool c2c = qnzb && knz && (kfr <= qfr);
        bool n2c = !qnzb && knz && (kfr < qfr);
        bool n2n = !qnzb && !knz && (kfr == qfr);
        int df = qfr - kfr; df = df < 0 ? -df : df;
        bool msk = (c2c || n2c || n2n) && ok && (df <= W);
        pv[nt][r] = msk ? sacc[nt][r] * scale : -1e9f;
      }
    }
    // online softmax
    for (int r = 0; r < 4; r++) {
      float mx = fmaxf(pv[0][r], pv[1][r]);
      for (int o = 1; o < 16; o <<= 1) mx = fmaxf(mx, __shfl_xor(mx, o));
      float mnew = fmaxf(m_i[r], mx);
      float alpha = __expf(m_i[r] - mnew);
      m_i[r] = mnew;
      pv[0][r] = __expf(pv[0][r] - mnew);
      pv[1][r] = __expf(pv[1][r] - mnew);
      float rs = pv[0][r] + pv[1][r];
      for (int o = 1; o < 16; o <<= 1) rs += __shfl_xor(rs, o);
      l_i[r] = l_i[r] * alpha + rs;
      for (int d = 0; d < 8; d++) oacc[d][r] *= alpha;
    }
    // P: C/D -> A layout via wave-local LDS round-trip
    for (int nt = 0; nt < 2; nt++)
      for (int r = 0; r < 4; r++)
        pshare[quad * 4 + r][nt * 16 + l16] = f2bf(pv[nt][r]);
    __asm__ __volatile__("s_waitcnt lgkmcnt(0)" ::: "memory");
    bf16x8 pf = *(const bf16x8*)&pshare[l16][quad * 8];
    for (int d = 0; d < 8; d++)
      oacc[d] = __builtin_amdgcn_mfma_f32_16x16x32_bf16(pf, vf[d], oacc[d], 0, 0, 0);
    // shift pipeline
    for (int nt = 0; nt < 2; nt++) {
      ak[nt] = ak2[nt];
      for (int ks = 0; ks < 4; ks++) kf[nt][ks] = kf2[nt][ks];
    }
    t = tn;
  }

  for (int r = 0; r < 4; r++) {
    int q = qbase + quad * 4 + r;
    float inv = (aq[r] & (1 << 9)) ? 1.0f / l_i[r] : 0.0f;
    for (int d = 0; d < 8; d++)
      ob[(size_t)q * D + h * 128 + d * 16 + l16] = f2bf(oacc[d][r] * inv);
  }
}

extern "C" void kernel_launch(void* const* d_in, const int* in_sizes, int n_in,
                              void* d_out, int out_size, void* d_ws, size_t ws_size,
                              hipStream_t stream) {
  const float* x  = (const float*)d_in[0];
  const float* Wq = (const float*)d_in[1];
  const float* bq = (const float*)d_in[2];
  const float* Wk = (const float*)d_in[3];
  const float* bk = (const float*)d_in[4];
  const float* Wv = (const float*)d_in[5];
  const float* bv = (const float*)d_in[6];
  const float* gq = (const float*)d_in[7];
  const float* gk = (const float*)d_in[8];
  const float* Wo = (const float*)d_in[9];
  const float* bo = (const float*)d_in[10];
  const int* seq  = (const int*)d_in[11];
  const int* fr   = (const int*)d_in[12];
  const int* nz   = (const int*)d_in[13];
  const int* wsz  = (const int*)d_in[14];
  float* out = (float*)d_out;
  const int S = in_sizes[11];   // 3072
  const int D = 1536;

  char* ws = (char*)d_ws;
  size_t off = 0;
  unsigned short* x_bf = (unsigned short*)(ws + off); off += (size_t)S * D * 2;        // 9.4MB
  unsigned short* wt   = (unsigned short*)(ws + off); off += (size_t)3 * D * D * 2;    // 14.2MB
  float*          linq = (float*)(ws + off);          off += (size_t)S * D * 4;        // 18.9MB
  float*          link = (float*)(ws + off);          off += (size_t)S * D * 4;        // 18.9MB
  unsigned short* q_bf = (unsigned short*)(ws + off); off += (size_t)S * D * 2;
  unsigned short* k_bf = (unsigned short*)(ws + off); off += (size_t)S * D * 2;
  unsigned short* vtb  = (unsigned short*)(ws + off); off += (size_t)S * D * 2;
  unsigned short* o_bf = (unsigned short*)(ws + off); off += (size_t)S * D * 2;
  int*            kid  = (int*)(ws + off);            off += (size_t)S * 4;
  unsigned int*   tmsk = (unsigned int*)(ws + off);   off += (size_t)(S / 32) * 4;

  dim3 blk(256);
  conv_f2bf<<<dim3((S * D / 4 + 255) / 256), blk, 0, stream>>>(x, x_bf, S * D / 4);
  prep_ids<<<dim3(1), blk, 0, stream>>>(seq, fr, nz, kid, tmsk, S);
  conv_wt3<<<dim3(D / 64, D / 64, 3), blk, 0, stream>>>(Wq, Wk, Wv, wt);
  gemm_qkv<<<dim3(S / 128, 3 * D / 128), blk, 0, stream>>>(x_bf, wt, bq, bk, bv,
                                                           linq, link, vtb, S);
  rms_bf16<<<dim3(S), blk, 0, stream>>>(linq, gq, q_bf);
  rms_bf16<<<dim3(S), blk, 0, stream>>>(link, gk, k_bf);
  attn<<<dim3(S / 16, D / 128), dim3(64), 0, stream>>>(q_bf, k_bf, vtb, kid, tmsk,
                                                       wsz, o_bf, S);
  conv_wt<<<dim3(D / 64, D / 64), blk, 0, stream>>>(Wo, wt, D, D);
  gemm128<<<dim3(S / 128, D / 128), blk, 0, stream>>>(o_bf, wt, bo, out, S, D, D);
}

// Round 4
// 362.925 us; speedup vs baseline: 2.8453x; 1.1733x over previous
//
#include <hip/hip_runtime.h>
#include <hip/hip_bf16.h>
#include <stdint.h>

typedef __bf16 bf16x8 __attribute__((ext_vector_type(8)));
typedef float f32x4 __attribute__((ext_vector_type(4)));

__device__ __forceinline__ unsigned short f2bf(float f) {
  union { float f; unsigned int u; } v; v.f = f;
  unsigned int u = v.u;
  unsigned int r = (u + 0x7fffu + ((u >> 16) & 1u)) >> 16;
  return (unsigned short)r;
}

// ---------------- elementwise fp32 -> bf16 (x) ----------------
__global__ __launch_bounds__(256) void conv_f2bf(const float* __restrict__ in,
                                                 unsigned short* __restrict__ out, int n4) {
  int i = blockIdx.x * 256 + threadIdx.x;
  if (i < n4) {
    float4 v = ((const float4*)in)[i];
    ushort4 o;
    o.x = f2bf(v.x); o.y = f2bf(v.y); o.z = f2bf(v.z); o.w = f2bf(v.w);
    ((ushort4*)out)[i] = o;
  }
}

// ---------------- pack ids + per-32-key-tile occupancy masks ----------------
// kid: valid<<9 | nz<<8 | frame(0..15) | seq<<10 ; tmask: nz0 frames lo16, nz1 hi16
__global__ __launch_bounds__(256) void prep_ids(const int* __restrict__ seq,
                                                const int* __restrict__ fr,
                                                const int* __restrict__ nz,
                                                int* __restrict__ kid,
                                                unsigned int* __restrict__ tmask, int S) {
  __shared__ int ks_[3072];
  int tid = threadIdx.x;
  for (int i = tid; i < S; i += 256) {
    int sq = seq[i];
    int v = (sq < 0) ? 0 : ((1 << 9) | ((nz[i] & 1) << 8) | (fr[i] & 15) | (sq << 10));
    ks_[i] = v; kid[i] = v;
  }
  __syncthreads();
  for (int t = tid; t < S / 32; t += 256) {
    unsigned int m = 0;
    for (int j = 0; j < 32; j++) {
      int a = ks_[t * 32 + j];
      if (a & (1 << 9)) m |= (a & (1 << 8)) ? (1u << (16 + (a & 15))) : (1u << (a & 15));
    }
    tmask[t] = m;
  }
}

// ---------------- Wq/Wk/Wv/Wo [K][N] fp32 -> Wt [4*1536][K] bf16 ----------------
__global__ __launch_bounds__(256) void conv_wt4(const float* __restrict__ W0,
                                                const float* __restrict__ W1,
                                                const float* __restrict__ W2,
                                                const float* __restrict__ W3,
                                                unsigned short* __restrict__ Wt) {
  const int K = 1536, N = 1536;
  const float* W = blockIdx.z == 0 ? W0 : (blockIdx.z == 1 ? W1 : (blockIdx.z == 2 ? W2 : W3));
  __shared__ __align__(16) unsigned short t[64][65];
  int k0 = blockIdx.x * 64, n0 = blockIdx.y * 64;
  for (int i = 0; i < 16; i++) {
    int e = threadIdx.x + i * 256;
    int r = e >> 6, c = e & 63;
    t[r][c] = f2bf(W[(size_t)(k0 + r) * N + n0 + c]);
  }
  __syncthreads();
  for (int i = 0; i < 16; i++) {
    int e = threadIdx.x + i * 256;
    int r = e >> 6, c = e & 63;
    Wt[(size_t)(blockIdx.z * 1536 + n0 + r) * K + k0 + c] = t[c][r];
  }
}

// ---------------- fused QKV GEMM: x_bf[S][1536] @ wt_cat[4608][1536]^T ----------
// region 0 -> linq fp32 (+bq), region 1 -> link fp32 (+bk),
// region 2 -> vtb bf16 tile-blocked [h][tile][128][32]
__global__ __launch_bounds__(256) void gemm_qkv(
    const unsigned short* __restrict__ A, const unsigned short* __restrict__ Bt,
    const float* __restrict__ bq, const float* __restrict__ bk, const float* __restrict__ bv,
    float* __restrict__ linq, float* __restrict__ link, unsigned short* __restrict__ vtb,
    int S) {
  const int K = 1536;
  __shared__ __align__(16) unsigned short As[128 * 64];
  __shared__ __align__(16) unsigned short Bs[128 * 64];
  int tid = threadIdx.x, wave = tid >> 6, lane = tid & 63;
  int quad = lane >> 4, l16 = lane & 15;
  int m0 = blockIdx.x * 128, n0 = blockIdx.y * 128;
  int wm = (wave & 1) * 64, wn = (wave >> 1) * 64;
  int lr = lane >> 3, lc = (lane & 7) * 8;
  f32x4 acc[4][4] = {};
  for (int k0 = 0; k0 < K; k0 += 64) {
    for (int c = 0; c < 4; c++) {
      int chunk = wave * 4 + c;
      int row = chunk * 8 + lr;
      const unsigned short* ga = &A[(size_t)(m0 + row) * K + k0 + lc];
      const unsigned short* gb = &Bt[(size_t)(n0 + row) * K + k0 + lc];
      __builtin_amdgcn_global_load_lds(
          (const __attribute__((address_space(1))) unsigned int*)ga,
          (__attribute__((address_space(3))) unsigned int*)(As + chunk * 512), 16, 0, 0);
      __builtin_amdgcn_global_load_lds(
          (const __attribute__((address_space(1))) unsigned int*)gb,
          (__attribute__((address_space(3))) unsigned int*)(Bs + chunk * 512), 16, 0, 0);
    }
    __syncthreads();
    for (int kk = 0; kk < 64; kk += 32) {
      bf16x8 af[4], bfr[4];
      for (int i = 0; i < 4; i++)
        af[i] = *(const bf16x8*)&As[(wm + i * 16 + l16) * 64 + kk + quad * 8];
      for (int j = 0; j < 4; j++)
        bfr[j] = *(const bf16x8*)&Bs[(wn + j * 16 + l16) * 64 + kk + quad * 8];
      for (int i = 0; i < 4; i++)
        for (int j = 0; j < 4; j++)
          acc[i][j] = __builtin_amdgcn_mfma_f32_16x16x32_bf16(af[i], bfr[j], acc[i][j], 0, 0, 0);
    }
    __syncthreads();
  }
  int region = (n0 >= 3072) ? 2 : (n0 >= 1536 ? 1 : 0);
  int cbase = n0 - region * 1536;
  if (region < 2) {
    float* lin = region == 0 ? linq : link;
    const float* bias = region == 0 ? bq : bk;
    for (int j = 0; j < 4; j++) {
      int col = cbase + wn + j * 16 + l16;
      float b = bias[col];
      for (int i = 0; i < 4; i++)
        for (int r = 0; r < 4; r++)
          lin[(size_t)(m0 + wm + i * 16 + quad * 4 + r) * 1536 + col] = acc[i][j][r] + b;
    }
  } else {
    for (int j = 0; j < 4; j++) {
      int d = cbase + wn + j * 16 + l16;    // 0..1535
      float b = bv[d];
      int hh = d >> 7, dd = d & 127;
      for (int i = 0; i < 4; i++)
        for (int r = 0; r < 4; r++) {
          int s = m0 + wm + i * 16 + quad * 4 + r;
          vtb[((size_t)(hh * 96 + (s >> 5)) * 128 + dd) * 32 + (s & 31)] = f2bf(acc[i][j][r] + b);
        }
    }
  }
}

// ---------------- GEMM 128x128 (Wo): fp32 out + bias ----------------
__global__ __launch_bounds__(256) void gemm128(
    const unsigned short* __restrict__ A, const unsigned short* __restrict__ Bt,
    const float* __restrict__ bias, float* __restrict__ C, int M, int N, int K) {
  __shared__ __align__(16) unsigned short As[128 * 64];
  __shared__ __align__(16) unsigned short Bs[128 * 64];
  int tid = threadIdx.x, wave = tid >> 6, lane = tid & 63;
  int quad = lane >> 4, l16 = lane & 15;
  int m0 = blockIdx.x * 128, n0 = blockIdx.y * 128;
  int wm = (wave & 1) * 64, wn = (wave >> 1) * 64;
  int lr = lane >> 3, lc = (lane & 7) * 8;
  f32x4 acc[4][4] = {};
  for (int k0 = 0; k0 < K; k0 += 64) {
    for (int c = 0; c < 4; c++) {
      int chunk = wave * 4 + c;
      int row = chunk * 8 + lr;
      const unsigned short* ga = &A[(size_t)(m0 + row) * K + k0 + lc];
      const unsigned short* gb = &Bt[(size_t)(n0 + row) * K + k0 + lc];
      __builtin_amdgcn_global_load_lds(
          (const __attribute__((address_space(1))) unsigned int*)ga,
          (__attribute__((address_space(3))) unsigned int*)(As + chunk * 512), 16, 0, 0);
      __builtin_amdgcn_global_load_lds(
          (const __attribute__((address_space(1))) unsigned int*)gb,
          (__attribute__((address_space(3))) unsigned int*)(Bs + chunk * 512), 16, 0, 0);
    }
    __syncthreads();
    for (int kk = 0; kk < 64; kk += 32) {
      bf16x8 af[4], bfr[4];
      for (int i = 0; i < 4; i++)
        af[i] = *(const bf16x8*)&As[(wm + i * 16 + l16) * 64 + kk + quad * 8];
      for (int j = 0; j < 4; j++)
        bfr[j] = *(const bf16x8*)&Bs[(wn + j * 16 + l16) * 64 + kk + quad * 8];
      for (int i = 0; i < 4; i++)
        for (int j = 0; j < 4; j++)
          acc[i][j] = __builtin_amdgcn_mfma_f32_16x16x32_bf16(af[i], bfr[j], acc[i][j], 0, 0, 0);
    }
    __syncthreads();
  }
  for (int j = 0; j < 4; j++) {
    int col = n0 + wn + j * 16 + l16;
    float b = bias[col];
    for (int i = 0; i < 4; i++)
      for (int r = 0; r < 4; r++)
        C[(size_t)(m0 + wm + i * 16 + quad * 4 + r) * N + col] = acc[i][j][r] + b;
  }
}

// ---------------- RMS norm row-wise ----------------
__global__ __launch_bounds__(256) void rms_bf16(const float* __restrict__ lin,
                                                const float* __restrict__ g,
                                                unsigned short* __restrict__ out) {
  const int N = 1536;
  int row = blockIdx.x;
  const float* p = lin + (size_t)row * N;
  float vals[6];
  float ss = 0.f;
  for (int j = 0; j < 6; j++) {
    float v = p[threadIdx.x + j * 256];
    vals[j] = v; ss += v * v;
  }
  for (int o = 32; o > 0; o >>= 1) ss += __shfl_down(ss, o);
  __shared__ float red[4];
  if ((threadIdx.x & 63) == 0) red[threadIdx.x >> 6] = ss;
  __syncthreads();
  float tot = red[0] + red[1] + red[2] + red[3];
  float sc = rsqrtf(tot * (1.0f / N) + 1e-5f);
  unsigned short* po = out + (size_t)row * N;
  for (int j = 0; j < 6; j++) {
    int c = threadIdx.x + j * 256;
    po[c] = f2bf(vals[j] * sc * g[c]);
  }
}

// ---------------- flash attention: block = 64 q x 1 head, LDS K/V double-buffered ----
// grid(12, 48): head = blockIdx.x, qgroup = blockIdx.y (XCD spread: linear%8=(h+4qg)%8)
__global__ __launch_bounds__(256) void attn(
    const unsigned short* __restrict__ qb, const unsigned short* __restrict__ kb,
    const unsigned short* __restrict__ vt,   // tile-blocked [h][96][128][32]
    const int* __restrict__ kid, const unsigned int* __restrict__ tmask,
    const int* __restrict__ wsz,
    unsigned short* __restrict__ ob, int S) {
  const int D = 1536;
  const int h = blockIdx.x;
  const int q0 = blockIdx.y * 64;
  int tid = threadIdx.x, wave = tid >> 6, lane = tid & 63;
  int quad = lane >> 4, l16 = lane & 15;
  int W = wsz[0];
  const float scale = 0.088388347648318447f; // 1/sqrt(128)

  __shared__ __align__(16) unsigned short Ks[2][4096]; // [32 key][16 chunk sw: c^=key&15]
  __shared__ __align__(16) unsigned short Vs[2][4096]; // [128 row][4 chunk sw: c^=(row>>1)&3]
  __shared__ int kid_s[3072];
  __shared__ unsigned int tmask_s[96];
  __shared__ __align__(16) unsigned short pshare[4][16][40];

  for (int i = tid; i < 3072; i += 256) kid_s[i] = kid[i];
  if (tid < 96) tmask_s[tid] = tmask[tid];
  __syncthreads();

  // block-union allowed-frame mask over 64 q rows (lane -> one row)
  unsigned int allowed = 0;
  {
    int a = kid_s[q0 + lane];
    if (a & (1 << 9)) {
      int fq = a & 15, nq = (a >> 8) & 1;
      int lo = fq - W; if (lo < 0) lo = 0;
      unsigned int lom = ~((1u << lo) - 1);
      if (nq) allowed = (((1u << (fq + 1)) - 1) & lom) << 16;
      else    allowed = ((((1u << fq) - 1) & lom) << 16) | (1u << fq);
    }
    for (int o = 1; o < 64; o <<= 1) allowed |= __shfl_xor(allowed, o);
  }
  // per-wave allowed (rows repeat 4x across quads; OR over 64 lanes = 16-row union)
  unsigned int wallowed = 0;
  {
    int a = kid_s[q0 + wave * 16 + l16];
    if (a & (1 << 9)) {
      int fq = a & 15, nq = (a >> 8) & 1;
      int lo = fq - W; if (lo < 0) lo = 0;
      unsigned int lom = ~((1u << lo) - 1);
      if (nq) wallowed = (((1u << (fq + 1)) - 1) & lom) << 16;
      else    wallowed = ((((1u << fq) - 1) & lom) << 16) | (1u << fq);
    }
    for (int o = 1; o < 64; o <<= 1) wallowed |= __shfl_xor(wallowed, o);
  }

  // block-union live-tile bitmap
  unsigned long long bm0, bm1;
  {
    bm0 = __ballot((tmask_s[lane] & allowed) != 0);
    unsigned int tb = (lane < 32) ? tmask_s[64 + lane] : 0u;
    bm1 = __ballot((tb & allowed) != 0);
  }

  // Q fragments (A-operand)
  bf16x8 qf[4];
  {
    const unsigned short* qp = &qb[(size_t)(q0 + wave * 16 + l16) * D + h * 128 + quad * 8];
    for (int ks = 0; ks < 4; ks++) qf[ks] = *(const bf16x8*)&qp[ks * 32];
  }
  int aq[4];
  for (int r = 0; r < 4; r++) aq[r] = kid_s[q0 + wave * 16 + quad * 4 + r];

  f32x4 oacc[8] = {};
  float m_i[4], l_i[4];
  for (int r = 0; r < 4; r++) { m_i[r] = -1e9f; l_i[r] = 0.f; }

  const unsigned short* vth = vt + (size_t)h * 96 * 4096;

#define POP(dst) do { \
    if (bm0) { dst = __builtin_ctzll(bm0); bm0 &= bm0 - 1; } \
    else if (bm1) { dst = 64 + __builtin_ctzll(bm1); bm1 &= bm1 - 1; } \
    else dst = -1; } while (0)

#define STAGE(t_, b_) do { \
    for (int j = 0; j < 2; j++) { \
      int kl = wave * 8 + j * 4 + (lane >> 4); \
      int cc = (lane & 15) ^ (kl & 15); \
      const unsigned short* src = &kb[(size_t)((t_) * 32 + kl) * D + h * 128 + cc * 8]; \
      __builtin_amdgcn_global_load_lds( \
          (const __attribute__((address_space(1))) unsigned int*)src, \
          (__attribute__((address_space(3))) unsigned int*)(&Ks[b_][0] + wave * 1024 + j * 512), \
          16, 0, 0); \
    } \
    for (int j = 0; j < 2; j++) { \
      int idx = wave * 128 + j * 64 + lane; \
      int row = idx >> 2; \
      int cc = (idx & 3) ^ ((row >> 1) & 3); \
      const unsigned short* src = vth + (size_t)(t_) * 4096 + row * 32 + cc * 8; \
      __builtin_amdgcn_global_load_lds( \
          (const __attribute__((address_space(1))) unsigned int*)src, \
          (__attribute__((address_space(3))) unsigned int*)(&Vs[b_][0] + wave * 1024 + j * 512), \
          16, 0, 0); \
    } } while (0)

  int t;
  POP(t);
  if (t >= 0) STAGE(t, 0);
  __syncthreads();
  int buf = 0;

  while (t >= 0) {
    int tn;
    POP(tn);
    if (tn >= 0) STAGE(tn, buf ^ 1);

    if (wallowed & tmask_s[t]) {
      // QK^T from LDS K (swizzled)
      f32x4 sacc[2] = {};
      for (int nt = 0; nt < 2; nt++) {
        int key = nt * 16 + l16;
        for (int ks = 0; ks < 4; ks++) {
          int cc = (ks * 4 + quad) ^ l16;
          bf16x8 kf = *(const bf16x8*)&Ks[buf][(key * 16 + cc) * 8];
          sacc[nt] = __builtin_amdgcn_mfma_f32_16x16x32_bf16(qf[ks], kf, sacc[nt], 0, 0, 0);
        }
      }
      // mask
      int ak[2] = { kid_s[t * 32 + l16], kid_s[t * 32 + 16 + l16] };
      float pv[2][4];
      for (int nt = 0; nt < 2; nt++) {
        int a = ak[nt];
        int kfr = a & 15, knz = (a >> 8) & 1, kvb = (a >> 9) & 1, ksq = a >> 10;
        for (int r = 0; r < 4; r++) {
          int b = aq[r];
          int qfr = b & 15, qnzb = (b >> 8) & 1, qvb = (b >> 9) & 1, qsq = b >> 10;
          bool ok  = qvb && kvb && (qsq == ksq);
          bool c2c = qnzb && knz && (kfr <= qfr);
          bool n2c = !qnzb && knz && (kfr < qfr);
          bool n2n = !qnzb && !knz && (kfr == qfr);
          int df = qfr - kfr; df = df < 0 ? -df : df;
          bool msk = (c2c || n2c || n2n) && ok && (df <= W);
          pv[nt][r] = msk ? sacc[nt][r] * scale : -1e9f;
        }
      }
      // online softmax
      for (int r = 0; r < 4; r++) {
        float mx = fmaxf(pv[0][r], pv[1][r]);
        for (int o = 1; o < 16; o <<= 1) mx = fmaxf(mx, __shfl_xor(mx, o));
        float mnew = fmaxf(m_i[r], mx);
        float alpha = __expf(m_i[r] - mnew);
        m_i[r] = mnew;
        pv[0][r] = __expf(pv[0][r] - mnew);
        pv[1][r] = __expf(pv[1][r] - mnew);
        float rs = pv[0][r] + pv[1][r];
        for (int o = 1; o < 16; o <<= 1) rs += __shfl_xor(rs, o);
        l_i[r] = l_i[r] * alpha + rs;
        for (int d = 0; d < 8; d++) oacc[d][r] *= alpha;
      }
      // P: C/D -> A layout via wave-local LDS round-trip
      for (int nt = 0; nt < 2; nt++)
        for (int r = 0; r < 4; r++)
          pshare[wave][quad * 4 + r][nt * 16 + l16] = f2bf(pv[nt][r]);
      __asm__ __volatile__("s_waitcnt lgkmcnt(0)" ::: "memory");
      bf16x8 pf = *(const bf16x8*)&pshare[wave][l16][quad * 8];
      // PV from LDS V (swizzled)
      for (int d = 0; d < 8; d++) {
        int row = d * 16 + l16;
        int cc = quad ^ ((l16 >> 1) & 3);
        bf16x8 vf = *(const bf16x8*)&Vs[buf][(row * 4 + cc) * 8];
        oacc[d] = __builtin_amdgcn_mfma_f32_16x16x32_bf16(pf, vf, oacc[d], 0, 0, 0);
      }
    }
    __syncthreads();   // staged(tn) complete + all waves done reading buf
    buf ^= 1;
    t = tn;
  }
#undef POP
#undef STAGE

  for (int r = 0; r < 4; r++) {
    int q = q0 + wave * 16 + quad * 4 + r;
    float inv = (aq[r] & (1 << 9)) ? 1.0f / l_i[r] : 0.0f;
    for (int d = 0; d < 8; d++)
      ob[(size_t)q * D + h * 128 + d * 16 + l16] = f2bf(oacc[d][r] * inv);
  }
}

extern "C" void kernel_launch(void* const* d_in, const int* in_sizes, int n_in,
                              void* d_out, int out_size, void* d_ws, size_t ws_size,
                              hipStream_t stream) {
  const float* x  = (const float*)d_in[0];
  const float* Wq = (const float*)d_in[1];
  const float* bq = (const float*)d_in[2];
  const float* Wk = (const float*)d_in[3];
  const float* bk = (const float*)d_in[4];
  const float* Wv = (const float*)d_in[5];
  const float* bv = (const float*)d_in[6];
  const float* gq = (const float*)d_in[7];
  const float* gk = (const float*)d_in[8];
  const float* Wo = (const float*)d_in[9];
  const float* bo = (const float*)d_in[10];
  const int* seq  = (const int*)d_in[11];
  const int* fr   = (const int*)d_in[12];
  const int* nz   = (const int*)d_in[13];
  const int* wsz  = (const int*)d_in[14];
  float* out = (float*)d_out;
  const int S = in_sizes[11];   // 3072
  const int D = 1536;

  char* ws = (char*)d_ws;
  size_t off = 0;
  unsigned short* x_bf = (unsigned short*)(ws + off); off += (size_t)S * D * 2;
  unsigned short* wt   = (unsigned short*)(ws + off); off += (size_t)4 * D * D * 2;
  float*          linq = (float*)(ws + off);          off += (size_t)S * D * 4;
  float*          link = (float*)(ws + off);          off += (size_t)S * D * 4;
  unsigned short* q_bf = (unsigned short*)(ws + off); off += (size_t)S * D * 2;
  unsigned short* k_bf = (unsigned short*)(ws + off); off += (size_t)S * D * 2;
  unsigned short* vtb  = (unsigned short*)(ws + off); off += (size_t)S * D * 2;
  unsigned short* o_bf = (unsigned short*)(ws + off); off += (size_t)S * D * 2;
  int*            kid  = (int*)(ws + off);            off += (size_t)S * 4;
  unsigned int*   tmsk = (unsigned int*)(ws + off);   off += (size_t)(S / 32) * 4;

  dim3 blk(256);
  conv_f2bf<<<dim3((S * D / 4 + 255) / 256), blk, 0, stream>>>(x, x_bf, S * D / 4);
  prep_ids<<<dim3(1), blk, 0, stream>>>(seq, fr, nz, kid, tmsk, S);
  conv_wt4<<<dim3(D / 64, D / 64, 4), blk, 0, stream>>>(Wq, Wk, Wv, Wo, wt);
  gemm_qkv<<<dim3(S / 128, 3 * D / 128), blk, 0, stream>>>(x_bf, wt, bq, bk, bv,
                                                           linq, link, vtb, S);
  rms_bf16<<<dim3(S), blk, 0, stream>>>(linq, gq, q_bf);
  rms_bf16<<<dim3(S), blk, 0, stream>>>(link, gk, k_bf);
  attn<<<dim3(D / 128, S / 64), blk, 0, stream>>>(q_bf, k_bf, vtb, kid, tmsk,
                                                  wsz, o_bf, S);
  gemm128<<<dim3(S / 128, D / 128), blk, 0, stream>>>(o_bf, wt + (size_t)3 * D * D,
                                                      bo, out, S, D, D);
}